// Round 19
// baseline (1497.679 us; speedup 1.0000x reference)
//
#include <hip/hip_runtime.h>

#define HID 512
#define G4 2048      // 4*HID
#define LSEQ 64
#define VOC 32000
#define EMBD 256
#define NBLK 32      // lstm blocks: 2 batch-groups x 16 col-blocks
#define NTHR 512     // 8 waves = 8 row-tiles (16 gate rows each)
#define HSTEP 16384  // u32 entries per per-step h buffer (64 KB): [b][col]

using s16x8 = __attribute__((ext_vector_type(8))) short;   // 8 bf16 (4 VGPR)
using f32x4 = __attribute__((ext_vector_type(4))) float;   // MFMA acc frag
using uintx4 = __attribute__((ext_vector_type(4))) unsigned; // 16B payload

__device__ inline unsigned short f2bf_rn(float x) {
    unsigned u = __float_as_uint(x);
    unsigned r = (u + 0x7fffu + ((u >> 16) & 1u)) >> 16;
    return (unsigned short)r;
}
__device__ inline float bf2f(unsigned short h) {
    return __uint_as_float(((unsigned)h) << 16);
}
__device__ inline void gload_lds16(const void* g, void* l) {
    __builtin_amdgcn_global_load_lds(
        (const __attribute__((address_space(1))) void*)g,
        (__attribute__((address_space(3))) void*)l, 16, 0, 0);
}

// ---------------------------------------------------------------------------
// Kernel 1 (merged): z<2 -> input projection (encoder/decoder), producing
// xwT[(t*2048 + g*512 + col)*32 + b]; z==2 -> WhhE/WhhD f32 -> bf16 hi/lo
// planes (convWhh, 1024 blocks' worth of work).
// ---------------------------------------------------------------------------
__global__ __launch_bounds__(256) void input_proj_kernel(
    const int* __restrict__ Xtok, const int* __restrict__ Ytok,
    const float* __restrict__ embX, const float* __restrict__ embY,
    const float* __restrict__ WE, const float* __restrict__ WD,
    const float* __restrict__ bE, const float* __restrict__ bD,
    float* __restrict__ xwE, float* __restrict__ xwD,
    const float* __restrict__ WhhE, const float* __restrict__ WhhD,
    short* __restrict__ HiE, short* __restrict__ LoE,
    short* __restrict__ HiD, short* __restrict__ LoD)
{
    const int tid = threadIdx.x;
    const int phase = blockIdx.z;

    if (phase == 2) {                    // convWhh plane
        int blk = blockIdx.y * 32 + blockIdx.x;       // 0..1023
        int idx = blk * 256 + tid;                    // 2 mats x 131072 chunks
        int m = idx >> 17;
        int e = idx & 131071;
        const float* W = m ? WhhD : WhhE;
        short* Hi = m ? HiD : HiE;
        short* Lo = m ? LoD : LoE;
        size_t e0 = (size_t)e * 8;
        float4 v0 = *(const float4*)&W[e0];
        float4 v1 = *(const float4*)&W[e0 + 4];
        float xs[8] = {v0.x, v0.y, v0.z, v0.w, v1.x, v1.y, v1.z, v1.w};
        s16x8 h8, l8;
#pragma unroll
        for (int j = 0; j < 8; ++j) {
            unsigned short hi = f2bf_rn(xs[j]);
            h8[j] = (short)hi;
            l8[j] = (short)f2bf_rn(xs[j] - bf2f(hi));
        }
        *(s16x8*)&Hi[e0] = h8;
        *(s16x8*)&Lo[e0] = l8;
        return;
    }

    __shared__ float Al[32][68];
    __shared__ float Bl[32][68];
    __shared__ float Cl[64][68];
    const int* tokens = phase ? Ytok : Xtok;
    const float* emb  = phase ? embY : embX;
    const float* W    = phase ? WD : WE;
    const float* bv   = phase ? bD : bE;
    float* outp       = phase ? xwD : xwE;

    const int m0 = blockIdx.x * 64;
    const int n0 = blockIdx.y * 64;
    const int tm = tid & 15;
    const int tn = tid >> 4;

    float acc[4][4] = {};

    for (int kc = 0; kc < EMBD; kc += 32) {
#pragma unroll
        for (int r = 0; r < 2; ++r) {
            int i = tid + r * 256;
            int am = i >> 3;
            int kq = i & 7;
            int m = m0 + am;
            int t = m >> 5, b = m & 31;
            int tok;
            if (phase) { int tt = (t == 0) ? 0 : (t - 1); tok = tokens[b * LSEQ + tt]; }
            else       { tok = tokens[b * LSEQ + t]; }
            float4 av = *(const float4*)&emb[(size_t)tok * EMBD + kc + kq * 4];
            Al[kq * 4 + 0][am] = av.x; Al[kq * 4 + 1][am] = av.y;
            Al[kq * 4 + 2][am] = av.z; Al[kq * 4 + 3][am] = av.w;
            float4 wv = *(const float4*)&W[(size_t)(n0 + am) * EMBD + kc + kq * 4];
            Bl[kq * 4 + 0][am] = wv.x; Bl[kq * 4 + 1][am] = wv.y;
            Bl[kq * 4 + 2][am] = wv.z; Bl[kq * 4 + 3][am] = wv.w;
        }
        __syncthreads();
#pragma unroll
        for (int k = 0; k < 32; ++k) {
            float4 a  = *(const float4*)&Al[k][tm * 4];
            float4 b4 = *(const float4*)&Bl[k][tn * 4];
            acc[0][0] += a.x * b4.x; acc[0][1] += a.x * b4.y; acc[0][2] += a.x * b4.z; acc[0][3] += a.x * b4.w;
            acc[1][0] += a.y * b4.x; acc[1][1] += a.y * b4.y; acc[1][2] += a.y * b4.z; acc[1][3] += a.y * b4.w;
            acc[2][0] += a.z * b4.x; acc[2][1] += a.z * b4.y; acc[2][2] += a.z * b4.z; acc[2][3] += a.z * b4.w;
            acc[3][0] += a.w * b4.x; acc[3][1] += a.w * b4.y; acc[3][2] += a.w * b4.z; acc[3][3] += a.w * b4.w;
        }
        __syncthreads();
    }

    float4 bb = *(const float4*)&bv[n0 + tn * 4];
#pragma unroll
    for (int r = 0; r < 4; ++r) {
        Cl[tn * 4 + 0][tm * 4 + r] = acc[r][0] + bb.x;
        Cl[tn * 4 + 1][tm * 4 + r] = acc[r][1] + bb.y;
        Cl[tn * 4 + 2][tm * 4 + r] = acc[r][2] + bb.z;
        Cl[tn * 4 + 3][tm * 4 + r] = acc[r][3] + bb.w;
    }
    __syncthreads();

    const int t0 = m0 >> 5;
#pragma unroll
    for (int r = 0; r < 4; ++r) {
        int f = tid + r * 256;
        int nl = f >> 4;
        int rem = f & 15;
        int tp = rem >> 3;
        int bq = rem & 7;
        float4 v = *(const float4*)&Cl[nl][tp * 32 + bq * 4];
        *(float4*)&outp[((size_t)(t0 + tp) * G4 + n0 + nl) * 32 + bq * 4] = v;
    }
}

// ---------------------------------------------------------------------------
// Kernel 2: LSTM recurrence on matrix cores — batch-grouped exchange with
// PER-WAVE release-counters. R17 geometry: 2 groups x 16 blocks; block owns
// 32 h-cols; 8 waves = 8 row-tiles of 16 (rows m = c*4+gate, C-frag reg r =
// gate r). Per step: poll 16 group counters (f >= 8*s means all waves of all
// group blocks published H[s]); stage (4 x 16B sc1 + 4 x ds_write_b128,
// bijective XOR swizzle); B1; 16kt x {2 x ds_read_b128 + unpack + 3 MFMA};
// in-reg gates; publish u32; PER-WAVE vmcnt(0) drain; lane0 RELEASE
// atomic_add(counter, 1). No end-of-step barrier: hbu WAR is protocol-
// guaranteed (a wave writes s+1 only after observing all local publishes of
// step s, which data-depend on their step-s ds_reads).
// ---------------------------------------------------------------------------
__global__ __launch_bounds__(512, 2) void lstm_coop_kernel(
    const float* __restrict__ xwE, const float* __restrict__ xwD,
    const short* __restrict__ WhE_hi, const short* __restrict__ WhE_lo,
    const short* __restrict__ WhD_hi, const short* __restrict__ WhD_lo,
    unsigned* __restrict__ H32, int* __restrict__ flags)
{
    __shared__ unsigned hbu[16 * 512];   // 32 KB, [b_local][col] u32, swizzled

    const int tid = threadIdx.x;
    const int bid = blockIdx.x;
    const int g  = bid >> 4;             // batch group 0..1
    const int kb = bid & 15;             // col-block within group
    const int c0 = kb * 32;              // first of 32 owned cols
    const int gb0 = g * 16;              // group's first global batch
    const int lane = tid & 63;
    const int w = tid >> 6;              // 8 waves = 8 row-tiles
    const int arow = lane & 15;          // A-frag row within tile
    const int koffq = (lane >> 4) * 2;   // quad base within kt
    // B-frag read bases (local batch row, swizzled)
    const int bbl = lane & 15;
    const unsigned keyr = (unsigned)(bbl & 7);
    const unsigned rb0 = (unsigned)bbl * 2048 + (((unsigned)koffq ^ keyr) << 4);
    const unsigned rb1 = (unsigned)bbl * 2048 + (((unsigned)(koffq + 1) ^ keyr) << 4);
    // staging: local row sbl = 2w + (lane>>5), quad sq = lane&31 (+32k)
    const int sbl = 2 * w + (lane >> 5);
    const int sq = lane & 31;
    const unsigned wswz = (((unsigned)(sq & 7) ^ (unsigned)(sbl & 7)) | (unsigned)(sq & 24));
    const unsigned wbase = (unsigned)sbl * 2048 + (wswz << 4);
    // output mapping
    const int col0 = c0 + 4 * w + (lane >> 4);
    const int bpub = gb0 + (lane & 15);
    float creg = 0.f;

    s16x8 AH[16], AL[16];                // Whh hi/lo frags (per-phase resident)

    for (int s = 0; s < 2 * LSEQ; ++s) {
        const int phase = s >> 6;
        const int t = s & 63;
        if (t == 0) {                    // (re)load A frags for this phase
            const short* WH = phase ? WhD_hi : WhE_hi;
            const short* WL = phase ? WhD_lo : WhE_lo;
            const int gr = (arow & 3) * 512 + c0 + 4 * w + (arow >> 2);
            const size_t ab = (size_t)gr * 512 + (lane >> 4) * 8;
#pragma unroll
            for (int kt = 0; kt < 16; ++kt) {
                AH[kt] = *(const s16x8*)&WH[ab + kt * 32];
                AL[kt] = *(const s16x8*)&WL[ab + kt * 32];
            }
        }

        // xw prefetch (h-independent; drained by the staging vmcnt(0))
        const float* xw = phase ? xwD : xwE;
        size_t xb = ((size_t)t * G4 + col0) * 32 + bpub;
        float xg0 = xw[xb];
        float xg1 = xw[xb + 1 * 512 * 32];
        float xg2 = xw[xb + 2 * 512 * 32];
        float xg3 = xw[xb + 3 * 512 * 32];

        // poll this group's 16 wave-counters (target 8*s) — one wave-load/round
        {
            const int* flagp = flags + (g * 16 + (lane & 15)) * 32;  // 128B lines
            const int tgt = 8 * s;
            for (;;) {
                int f = __hip_atomic_load(flagp, __ATOMIC_RELAXED,
                                          __HIP_MEMORY_SCOPE_AGENT);
                if (__all(f >= tgt)) break;
                __builtin_amdgcn_s_sleep(1);
            }
        }
        __builtin_amdgcn_sched_barrier(0);

        // stage: 4 x 16B sc1 loads -> ONE vmcnt(0) -> 4 x ds_write_b128
        const char* sbase = (const char*)(H32 + (size_t)s * HSTEP
                                          + (size_t)(gb0 + sbl) * 512) + sq * 16;
        uintx4 v[4];
#pragma unroll
        for (int k = 0; k < 4; ++k)
            asm volatile("global_load_dwordx4 %0, %1, off offset:%c2 sc1"
                         : "=v"(v[k]) : "v"(sbase), "i"(k * 512));
        asm volatile("s_waitcnt vmcnt(0)" ::: "memory");
        __builtin_amdgcn_sched_barrier(0);
#pragma unroll
        for (int k = 0; k < 4; ++k)
            *(uintx4*)((char*)hbu + wbase + k * 512) = v[k];
        asm volatile("s_waitcnt lgkmcnt(0)\ns_barrier" ::: "memory");  // B1 (only barrier)

        // MFMA: per kt read one B-frag (2 x b128 swizzled), 3 MFMAs
        f32x4 a0 = {}, a1 = {}, a2 = {};
#pragma unroll
        for (int kt = 0; kt < 16; ++kt) {
            uintx4 q0 = *(const uintx4*)((const char*)hbu + rb0 + kt * 128);
            uintx4 q1 = *(const uintx4*)((const char*)hbu + rb1 + kt * 128);
            uintx4 bh, bl;
            bh[0] = (q0[0] & 0xffffu) | (q0[1] << 16);
            bh[1] = (q0[2] & 0xffffu) | (q0[3] << 16);
            bh[2] = (q1[0] & 0xffffu) | (q1[1] << 16);
            bh[3] = (q1[2] & 0xffffu) | (q1[3] << 16);
            bl[0] = (q0[0] >> 16) | (q0[1] & 0xffff0000u);
            bl[1] = (q0[2] >> 16) | (q0[3] & 0xffff0000u);
            bl[2] = (q1[0] >> 16) | (q1[1] & 0xffff0000u);
            bl[3] = (q1[2] >> 16) | (q1[3] & 0xffff0000u);
            s16x8 bhv = __builtin_bit_cast(s16x8, bh);
            s16x8 blv = __builtin_bit_cast(s16x8, bl);
            a0 = __builtin_amdgcn_mfma_f32_16x16x32_bf16(AH[kt], bhv, a0, 0, 0, 0);
            a1 = __builtin_amdgcn_mfma_f32_16x16x32_bf16(AL[kt], bhv, a1, 0, 0, 0);
            a2 = __builtin_amdgcn_mfma_f32_16x16x32_bf16(AH[kt], blv, a2, 0, 0, 0);
        }

        // gates fully in-register (C-frag reg r = gate r); one publish/lane
        {
            float gi = xg0 + a0[0] + a1[0] + a2[0];
            float gf = xg1 + a0[1] + a1[1] + a2[1];
            float gg = xg2 + a0[2] + a1[2] + a2[2];
            float go = xg3 + a0[3] + a1[3] + a2[3];
            float si = 1.f / (1.f + __expf(-gi));
            float sf = 1.f / (1.f + __expf(-gf));
            float so = 1.f / (1.f + __expf(-go));
            float tg = tanhf(gg);
            float c = sf * creg + si * tg;
            creg = c;
            float h = so * tanhf(c);
            unsigned hi = f2bf_rn(h);
            unsigned lo = f2bf_rn(h - bf2f((unsigned short)hi));
            __hip_atomic_store(
                H32 + (size_t)(s + 1) * HSTEP + (size_t)bpub * 512 + col0,
                hi | (lo << 16), __ATOMIC_RELAXED, __HIP_MEMORY_SCOPE_AGENT);
        }
        // per-wave publish: drain OWN stores (vmcnt is per-wave), then count
        asm volatile("s_waitcnt vmcnt(0)" ::: "memory");
        __builtin_amdgcn_sched_barrier(0);
        if (lane == 0)
            __hip_atomic_fetch_add(&flags[bid * 32], 1,
                                   __ATOMIC_RELEASE, __HIP_MEMORY_SCOPE_AGENT);
        // no end-of-step barrier (protocol-guaranteed hbu WAR)
    }
}

// ---------------------------------------------------------------------------
// Kernel 4 (merged): bi<8000 -> fcW f32 -> Bhi bf16; bi>=8000 -> decoder H
// (u32 hilo, [b][col]) -> Ahi bf16 [2048][512].
// ---------------------------------------------------------------------------
__global__ __launch_bounds__(256) void convWA_kernel(
    const float* __restrict__ W, short* __restrict__ Bhi,
    const unsigned* __restrict__ H65, short* __restrict__ Ahi)
{
    const int bi = blockIdx.x;
    const int tid = threadIdx.x;
    if (bi < 8000) {
        size_t idx = (size_t)bi * 256 + tid;
        size_t e0 = idx * 8;
        float4 v0 = *(const float4*)&W[e0];
        float4 v1 = *(const float4*)&W[e0 + 4];
        float xs[8] = {v0.x, v0.y, v0.z, v0.w, v1.x, v1.y, v1.z, v1.w};
        s16x8 h8;
#pragma unroll
        for (int j = 0; j < 8; ++j)
            h8[j] = (short)f2bf_rn(xs[j]);
        *(s16x8*)&Bhi[e0] = h8;
    } else {
        int idx = (bi - 8000) * 256 + tid;   // 131072 = 2048 m x 64 k8
        int m = idx & 2047;
        int k8 = idx >> 11;
        int t = m >> 5, b = m & 31;
        const unsigned* Hs = H65 + (size_t)t * HSTEP;
        s16x8 h8;
#pragma unroll
        for (int j = 0; j < 8; ++j) {
            unsigned u = Hs[(size_t)b * 512 + k8 * 8 + j];
            h8[j] = (short)(u & 0xffffu);
        }
        *(s16x8*)&Ahi[(size_t)m * 512 + k8 * 8] = h8;
    }
}

// ---------------------------------------------------------------------------
// Kernel 5: FC as a plain bf16 MFMA GEMM: C = Ahi*Bhi (+bias). K = 512.
// 128x128 tile, 4 waves, K-step 64, global_load_lds(16), 16x16x32 bf16 MFMA.
// ---------------------------------------------------------------------------
__global__ __launch_bounds__(256) void fc_mfma_kernel(
    const short* __restrict__ Ahi, const short* __restrict__ Bhi,
    const float* __restrict__ bias, float* __restrict__ out)
{
    __shared__ short As[128 * 64];
    __shared__ short Bs[128 * 64];

    const int bi = blockIdx.x;
    const int wg = (bi & 7) * 500 + (bi >> 3);    // XCD-contiguous remap
    const int mt = wg & 15, nt = wg >> 4;
    const int m0 = mt * 128, n0 = nt * 128;
    const int tid = threadIdx.x;
    const int w = tid >> 6, lane = tid & 63;
    const int wm = w >> 1, wn = w & 1;
    const int srow = (lane >> 3);
    const int scol = (lane & 7) * 8;

    f32x4 acc[4][4] = {};

    for (int ks = 0; ks < 8; ++ks) {
        const int kco = ks * 64;
#pragma unroll
        for (int i = 0; i < 4; ++i) {
            int row = w * 32 + i * 8 + srow;
            gload_lds16(&Ahi[(size_t)(m0 + row) * 512 + kco + scol],
                        (void*)&As[w * 2048 + i * 512]);
            gload_lds16(&Bhi[(size_t)(n0 + row) * 512 + kco + scol],
                        (void*)&Bs[w * 2048 + i * 512]);
        }
        __syncthreads();

#pragma unroll
        for (int kk = 0; kk < 2; ++kk) {
            s16x8 af[4], bf[4];
#pragma unroll
            for (int f = 0; f < 4; ++f) {
                af[f] = *(const s16x8*)&As[(wm * 64 + f * 16 + (lane & 15)) * 64 + kk * 32 + (lane >> 4) * 8];
                bf[f] = *(const s16x8*)&Bs[(wn * 64 + f * 16 + (lane & 15)) * 64 + kk * 32 + (lane >> 4) * 8];
            }
#pragma unroll
            for (int fm = 0; fm < 4; ++fm)
#pragma unroll
                for (int fn = 0; fn < 4; ++fn)
                    acc[fm][fn] = __builtin_amdgcn_mfma_f32_16x16x32_bf16(
                        af[fm], bf[fn], acc[fm][fn], 0, 0, 0);
        }
        __syncthreads();
    }

    float bb[4];
#pragma unroll
    for (int fn = 0; fn < 4; ++fn)
        bb[fn] = bias[n0 + wn * 64 + fn * 16 + (lane & 15)];

#pragma unroll
    for (int fm = 0; fm < 4; ++fm) {
        int mbase = m0 + wm * 64 + fm * 16 + (lane >> 4) * 4;
#pragma unroll
        for (int r = 0; r < 4; ++r) {
            int m = mbase + r;
            int t = m >> 5, b = m & 31;
            float* orow = out + (size_t)(b * LSEQ + t) * VOC;
#pragma unroll
            for (int fn = 0; fn < 4; ++fn)
                orow[n0 + wn * 64 + fn * 16 + (lane & 15)] = acc[fm][fn][r] + bb[fn];
        }
    }
}

// ---------------------------------------------------------------------------
extern "C" void kernel_launch(void* const* d_in, const int* in_sizes, int n_in,
                              void* d_out, int out_size, void* d_ws, size_t ws_size,
                              hipStream_t stream)
{
    const int*   X    = (const int*)d_in[0];
    const int*   y    = (const int*)d_in[1];
    // d_in[2] = teacher_forcing (always 1, unused)
    const float* embX = (const float*)d_in[3];
    const float* WihE = (const float*)d_in[4];
    const float* WhhE = (const float*)d_in[5];
    const float* bE   = (const float*)d_in[6];
    const float* embY = (const float*)d_in[7];
    const float* WihD = (const float*)d_in[8];
    const float* WhhD = (const float*)d_in[9];
    const float* bD   = (const float*)d_in[10];
    const float* fcW  = (const float*)d_in[11];
    const float* fcB  = (const float*)d_in[12];
    float* out = (float*)d_out;

    char* ws = (char*)d_ws;
    const size_t XW_BYTES = (size_t)2048 * 2048 * 4;          // 16 MB each
    const size_t FL_BYTES = 64 * 1024;                        // flags (4 KB used)
    const size_t H_BYTES  = (size_t)129 * HSTEP * 4;          // 8.45 MB
    const size_t A_BYTES  = (size_t)2048 * HID * 2;           // 2 MB
    const size_t WP_BYTES = (size_t)G4 * HID * 2;             // 2 MB per plane

    float*    xwE   = (float*)(ws);
    float*    xwD   = (float*)(ws + XW_BYTES);
    int*      flags = (int*)(ws + 2 * XW_BYTES);
    unsigned* H32   = (unsigned*)(ws + 2 * XW_BYTES + FL_BYTES);
    short*    Ahi   = (short*)(ws + 2 * XW_BYTES + FL_BYTES + H_BYTES);
    short*    Bhi   = (short*)(ws);                           // aliases xw (dead post-lstm)
    char*     Wplanes = ws + 2 * XW_BYTES + FL_BYTES + H_BYTES + 2 * A_BYTES;
    short* WhE_hi = (short*)(Wplanes);
    short* WhE_lo = (short*)(Wplanes + WP_BYTES);
    short* WhD_hi = (short*)(Wplanes + 2 * WP_BYTES);
    short* WhD_lo = (short*)(Wplanes + 3 * WP_BYTES);

    // reset flags + H[0] (= h0 = 0) each launch: 128 KB total
    hipMemsetAsync((void*)flags, 0, FL_BYTES + (size_t)HSTEP * 4, stream);

    input_proj_kernel<<<dim3(32, 32, 3), 256, 0, stream>>>(
        X, y, embX, embY, WihE, WihD, bE, bD, xwE, xwD,
        WhhE, WhhD, WhE_hi, WhE_lo, WhD_hi, WhD_lo);

    {
        const float* a0 = xwE; const float* a1 = xwD;
        const short* a2 = WhE_hi; const short* a3 = WhE_lo;
        const short* a4 = WhD_hi; const short* a5 = WhD_lo;
        unsigned* a6 = H32; int* a7 = flags;
        void* args[] = {&a0, &a1, &a2, &a3, &a4, &a5, &a6, &a7};
        hipLaunchCooperativeKernel((const void*)lstm_coop_kernel, dim3(NBLK), dim3(NTHR),
                                   args, 0, stream);
    }

    convWA_kernel<<<8512, 256, 0, stream>>>(fcW, Bhi, H32 + (size_t)65 * HSTEP, Ahi);

    fc_mfma_kernel<<<4000, 256, 0, stream>>>(Ahi, Bhi, fcB, out);
}

// Round 20
// 784.283 us; speedup vs baseline: 1.9096x; 1.9096x over previous
//
#include <hip/hip_runtime.h>

#define HID 512
#define G4 2048      // 4*HID
#define LSEQ 64
#define VOC 32000
#define EMBD 256
#define NBLK 32      // lstm blocks: 2 batch-groups x 16 col-blocks
#define NTHR 512     // 8 waves = 8 row-tiles (16 gate rows each)
#define HSTEP 16384  // u32 entries per per-step h buffer (64 KB): [b][col]

using s16x8 = __attribute__((ext_vector_type(8))) short;   // 8 bf16 (4 VGPR)
using f32x4 = __attribute__((ext_vector_type(4))) float;   // MFMA acc frag
using uintx4 = __attribute__((ext_vector_type(4))) unsigned; // 16B payload

__device__ inline unsigned short f2bf_rn(float x) {
    unsigned u = __float_as_uint(x);
    unsigned r = (u + 0x7fffu + ((u >> 16) & 1u)) >> 16;
    return (unsigned short)r;
}
__device__ inline float bf2f(unsigned short h) {
    return __uint_as_float(((unsigned)h) << 16);
}
__device__ inline void gload_lds16(const void* g, void* l) {
    __builtin_amdgcn_global_load_lds(
        (const __attribute__((address_space(1))) void*)g,
        (__attribute__((address_space(3))) void*)l, 16, 0, 0);
}

// ---------------------------------------------------------------------------
// Kernel 1 (merged): z<2 -> input projection (encoder/decoder), producing
// xwT[(t*2048 + g*512 + col)*32 + b]; z==2 -> WhhE/WhhD f32 -> bf16 hi/lo
// planes (convWhh, 1024 blocks' worth of work).
// ---------------------------------------------------------------------------
__global__ __launch_bounds__(256) void input_proj_kernel(
    const int* __restrict__ Xtok, const int* __restrict__ Ytok,
    const float* __restrict__ embX, const float* __restrict__ embY,
    const float* __restrict__ WE, const float* __restrict__ WD,
    const float* __restrict__ bE, const float* __restrict__ bD,
    float* __restrict__ xwE, float* __restrict__ xwD,
    const float* __restrict__ WhhE, const float* __restrict__ WhhD,
    short* __restrict__ HiE, short* __restrict__ LoE,
    short* __restrict__ HiD, short* __restrict__ LoD)
{
    const int tid = threadIdx.x;
    const int phase = blockIdx.z;

    if (phase == 2) {                    // convWhh plane
        int blk = blockIdx.y * 32 + blockIdx.x;       // 0..1023
        int idx = blk * 256 + tid;                    // 2 mats x 131072 chunks
        int m = idx >> 17;
        int e = idx & 131071;
        const float* W = m ? WhhD : WhhE;
        short* Hi = m ? HiD : HiE;
        short* Lo = m ? LoD : LoE;
        size_t e0 = (size_t)e * 8;
        float4 v0 = *(const float4*)&W[e0];
        float4 v1 = *(const float4*)&W[e0 + 4];
        float xs[8] = {v0.x, v0.y, v0.z, v0.w, v1.x, v1.y, v1.z, v1.w};
        s16x8 h8, l8;
#pragma unroll
        for (int j = 0; j < 8; ++j) {
            unsigned short hi = f2bf_rn(xs[j]);
            h8[j] = (short)hi;
            l8[j] = (short)f2bf_rn(xs[j] - bf2f(hi));
        }
        *(s16x8*)&Hi[e0] = h8;
        *(s16x8*)&Lo[e0] = l8;
        return;
    }

    __shared__ float Al[32][68];
    __shared__ float Bl[32][68];
    __shared__ float Cl[64][68];
    const int* tokens = phase ? Ytok : Xtok;
    const float* emb  = phase ? embY : embX;
    const float* W    = phase ? WD : WE;
    const float* bv   = phase ? bD : bE;
    float* outp       = phase ? xwD : xwE;

    const int m0 = blockIdx.x * 64;
    const int n0 = blockIdx.y * 64;
    const int tm = tid & 15;
    const int tn = tid >> 4;

    float acc[4][4] = {};

    for (int kc = 0; kc < EMBD; kc += 32) {
#pragma unroll
        for (int r = 0; r < 2; ++r) {
            int i = tid + r * 256;
            int am = i >> 3;
            int kq = i & 7;
            int m = m0 + am;
            int t = m >> 5, b = m & 31;
            int tok;
            if (phase) { int tt = (t == 0) ? 0 : (t - 1); tok = tokens[b * LSEQ + tt]; }
            else       { tok = tokens[b * LSEQ + t]; }
            float4 av = *(const float4*)&emb[(size_t)tok * EMBD + kc + kq * 4];
            Al[kq * 4 + 0][am] = av.x; Al[kq * 4 + 1][am] = av.y;
            Al[kq * 4 + 2][am] = av.z; Al[kq * 4 + 3][am] = av.w;
            float4 wv = *(const float4*)&W[(size_t)(n0 + am) * EMBD + kc + kq * 4];
            Bl[kq * 4 + 0][am] = wv.x; Bl[kq * 4 + 1][am] = wv.y;
            Bl[kq * 4 + 2][am] = wv.z; Bl[kq * 4 + 3][am] = wv.w;
        }
        __syncthreads();
#pragma unroll
        for (int k = 0; k < 32; ++k) {
            float4 a  = *(const float4*)&Al[k][tm * 4];
            float4 b4 = *(const float4*)&Bl[k][tn * 4];
            acc[0][0] += a.x * b4.x; acc[0][1] += a.x * b4.y; acc[0][2] += a.x * b4.z; acc[0][3] += a.x * b4.w;
            acc[1][0] += a.y * b4.x; acc[1][1] += a.y * b4.y; acc[1][2] += a.y * b4.z; acc[1][3] += a.y * b4.w;
            acc[2][0] += a.z * b4.x; acc[2][1] += a.z * b4.y; acc[2][2] += a.z * b4.z; acc[2][3] += a.z * b4.w;
            acc[3][0] += a.w * b4.x; acc[3][1] += a.w * b4.y; acc[3][2] += a.w * b4.z; acc[3][3] += a.w * b4.w;
        }
        __syncthreads();
    }

    float4 bb = *(const float4*)&bv[n0 + tn * 4];
#pragma unroll
    for (int r = 0; r < 4; ++r) {
        Cl[tn * 4 + 0][tm * 4 + r] = acc[r][0] + bb.x;
        Cl[tn * 4 + 1][tm * 4 + r] = acc[r][1] + bb.y;
        Cl[tn * 4 + 2][tm * 4 + r] = acc[r][2] + bb.z;
        Cl[tn * 4 + 3][tm * 4 + r] = acc[r][3] + bb.w;
    }
    __syncthreads();

    const int t0 = m0 >> 5;
#pragma unroll
    for (int r = 0; r < 4; ++r) {
        int f = tid + r * 256;
        int nl = f >> 4;
        int rem = f & 15;
        int tp = rem >> 3;
        int bq = rem & 7;
        float4 v = *(const float4*)&Cl[nl][tp * 32 + bq * 4];
        *(float4*)&outp[((size_t)(t0 + tp) * G4 + n0 + nl) * 32 + bq * 4] = v;
    }
}

// ---------------------------------------------------------------------------
// Kernel 2: LSTM recurrence on matrix cores — batch-grouped exchange.
// EXACT R17/R18 protocol (best measured: 542 us; R19's per-wave RMW counters
// regressed 2.5x -> reverted). 2 groups x 16 blocks; group g owns batches
// 16g..16g+15; block (g,kb) owns 32 h-cols (128 gate rows). 8 waves = 8
// row-tiles of 16 (rows m = c*4+gate, C-frag reg r = gate r). Per step:
// poll 16 group flags (f >= s, one wave-load/round); stage (4 x 16B sc1 +
// 4 x ds_write_b128, bijective XOR swizzle); B1; 16kt x {2 x ds_read_b128 +
// unpack + 3 MFMA}; in-reg gates; publish u32; __syncthreads (vmcnt0 drain,
// in-CU join); tid0 single RELEASE flag store.
// ---------------------------------------------------------------------------
__global__ __launch_bounds__(512, 2) void lstm_coop_kernel(
    const float* __restrict__ xwE, const float* __restrict__ xwD,
    const short* __restrict__ WhE_hi, const short* __restrict__ WhE_lo,
    const short* __restrict__ WhD_hi, const short* __restrict__ WhD_lo,
    unsigned* __restrict__ H32, int* __restrict__ flags)
{
    __shared__ unsigned hbu[16 * 512];   // 32 KB, [b_local][col] u32, swizzled

    const int tid = threadIdx.x;
    const int bid = blockIdx.x;
    const int g  = bid >> 4;             // batch group 0..1
    const int kb = bid & 15;             // col-block within group
    const int c0 = kb * 32;              // first of 32 owned cols
    const int gb0 = g * 16;              // group's first global batch
    const int lane = tid & 63;
    const int w = tid >> 6;              // 8 waves = 8 row-tiles
    const int arow = lane & 15;          // A-frag row within tile
    const int koffq = (lane >> 4) * 2;   // quad base within kt
    // B-frag read bases (local batch row, swizzled)
    const int bbl = lane & 15;
    const unsigned keyr = (unsigned)(bbl & 7);
    const unsigned rb0 = (unsigned)bbl * 2048 + (((unsigned)koffq ^ keyr) << 4);
    const unsigned rb1 = (unsigned)bbl * 2048 + (((unsigned)(koffq + 1) ^ keyr) << 4);
    // staging: local row sbl = 2w + (lane>>5), quad sq = lane&31 (+32k)
    const int sbl = 2 * w + (lane >> 5);
    const int sq = lane & 31;
    const unsigned wswz = (((unsigned)(sq & 7) ^ (unsigned)(sbl & 7)) | (unsigned)(sq & 24));
    const unsigned wbase = (unsigned)sbl * 2048 + (wswz << 4);
    // output mapping
    const int col0 = c0 + 4 * w + (lane >> 4);
    const int bpub = gb0 + (lane & 15);
    float creg = 0.f;

    s16x8 AH[16], AL[16];                // Whh hi/lo frags (per-phase resident)

    for (int s = 0; s < 2 * LSEQ; ++s) {
        const int phase = s >> 6;
        const int t = s & 63;
        if (t == 0) {                    // (re)load A frags for this phase
            const short* WH = phase ? WhD_hi : WhE_hi;
            const short* WL = phase ? WhD_lo : WhE_lo;
            const int gr = (arow & 3) * 512 + c0 + 4 * w + (arow >> 2);
            const size_t ab = (size_t)gr * 512 + (lane >> 4) * 8;
#pragma unroll
            for (int kt = 0; kt < 16; ++kt) {
                AH[kt] = *(const s16x8*)&WH[ab + kt * 32];
                AL[kt] = *(const s16x8*)&WL[ab + kt * 32];
            }
        }

        // xw prefetch (h-independent; drained by the staging vmcnt(0))
        const float* xw = phase ? xwD : xwE;
        size_t xb = ((size_t)t * G4 + col0) * 32 + bpub;
        float xg0 = xw[xb];
        float xg1 = xw[xb + 1 * 512 * 32];
        float xg2 = xw[xb + 2 * 512 * 32];
        float xg3 = xw[xb + 3 * 512 * 32];

        // poll this group's 16 producer flags with one wave-load per round
        {
            const int* flagp = flags + (g * 16 + (lane & 15)) * 32;  // 128B lines
            for (;;) {
                int f = __hip_atomic_load(flagp, __ATOMIC_RELAXED,
                                          __HIP_MEMORY_SCOPE_AGENT);
                if (__all(f >= s)) break;
                __builtin_amdgcn_s_sleep(1);
            }
        }
        __builtin_amdgcn_sched_barrier(0);

        // stage: 4 x 16B sc1 loads -> ONE vmcnt(0) -> 4 x ds_write_b128
        const char* sbase = (const char*)(H32 + (size_t)s * HSTEP
                                          + (size_t)(gb0 + sbl) * 512) + sq * 16;
        uintx4 v[4];
#pragma unroll
        for (int k = 0; k < 4; ++k)
            asm volatile("global_load_dwordx4 %0, %1, off offset:%c2 sc1"
                         : "=v"(v[k]) : "v"(sbase), "i"(k * 512));
        asm volatile("s_waitcnt vmcnt(0)" ::: "memory");
        __builtin_amdgcn_sched_barrier(0);
#pragma unroll
        for (int k = 0; k < 4; ++k)
            *(uintx4*)((char*)hbu + wbase + k * 512) = v[k];
        asm volatile("s_waitcnt lgkmcnt(0)\ns_barrier" ::: "memory");  // B1

        // MFMA: per kt read one B-frag (2 x b128 swizzled), 3 MFMAs
        f32x4 a0 = {}, a1 = {}, a2 = {};
#pragma unroll
        for (int kt = 0; kt < 16; ++kt) {
            uintx4 q0 = *(const uintx4*)((const char*)hbu + rb0 + kt * 128);
            uintx4 q1 = *(const uintx4*)((const char*)hbu + rb1 + kt * 128);
            uintx4 bh, bl;
            bh[0] = (q0[0] & 0xffffu) | (q0[1] << 16);
            bh[1] = (q0[2] & 0xffffu) | (q0[3] << 16);
            bh[2] = (q1[0] & 0xffffu) | (q1[1] << 16);
            bh[3] = (q1[2] & 0xffffu) | (q1[3] << 16);
            bl[0] = (q0[0] >> 16) | (q0[1] & 0xffff0000u);
            bl[1] = (q0[2] >> 16) | (q0[3] & 0xffff0000u);
            bl[2] = (q1[0] >> 16) | (q1[1] & 0xffff0000u);
            bl[3] = (q1[2] >> 16) | (q1[3] & 0xffff0000u);
            s16x8 bhv = __builtin_bit_cast(s16x8, bh);
            s16x8 blv = __builtin_bit_cast(s16x8, bl);
            a0 = __builtin_amdgcn_mfma_f32_16x16x32_bf16(AH[kt], bhv, a0, 0, 0, 0);
            a1 = __builtin_amdgcn_mfma_f32_16x16x32_bf16(AL[kt], bhv, a1, 0, 0, 0);
            a2 = __builtin_amdgcn_mfma_f32_16x16x32_bf16(AH[kt], blv, a2, 0, 0, 0);
        }

        // gates fully in-register (C-frag reg r = gate r); one publish/lane
        {
            float gi = xg0 + a0[0] + a1[0] + a2[0];
            float gf = xg1 + a0[1] + a1[1] + a2[1];
            float gg = xg2 + a0[2] + a1[2] + a2[2];
            float go = xg3 + a0[3] + a1[3] + a2[3];
            float si = 1.f / (1.f + __expf(-gi));
            float sf = 1.f / (1.f + __expf(-gf));
            float so = 1.f / (1.f + __expf(-go));
            float tg = tanhf(gg);
            float c = sf * creg + si * tg;
            creg = c;
            float h = so * tanhf(c);
            unsigned hi = f2bf_rn(h);
            unsigned lo = f2bf_rn(h - bf2f((unsigned short)hi));
            __hip_atomic_store(
                H32 + (size_t)(s + 1) * HSTEP + (size_t)bpub * 512 + col0,
                hi | (lo << 16), __ATOMIC_RELAXED, __HIP_MEMORY_SCOPE_AGENT);
        }
        __syncthreads();   // vmcnt(0) drain + in-CU block join
        if (tid == 0)
            __hip_atomic_store(&flags[bid * 32], s + 1,
                               __ATOMIC_RELEASE, __HIP_MEMORY_SCOPE_AGENT);
    }
}

// ---------------------------------------------------------------------------
// Kernel 4 (merged): bi<8000 -> fcW f32 -> Bhi bf16; bi>=8000 -> decoder H
// (u32 hilo, [b][col]) -> Ahi bf16 [2048][512].
// ---------------------------------------------------------------------------
__global__ __launch_bounds__(256) void convWA_kernel(
    const float* __restrict__ W, short* __restrict__ Bhi,
    const unsigned* __restrict__ H65, short* __restrict__ Ahi)
{
    const int bi = blockIdx.x;
    const int tid = threadIdx.x;
    if (bi < 8000) {
        size_t idx = (size_t)bi * 256 + tid;
        size_t e0 = idx * 8;
        float4 v0 = *(const float4*)&W[e0];
        float4 v1 = *(const float4*)&W[e0 + 4];
        float xs[8] = {v0.x, v0.y, v0.z, v0.w, v1.x, v1.y, v1.z, v1.w};
        s16x8 h8;
#pragma unroll
        for (int j = 0; j < 8; ++j)
            h8[j] = (short)f2bf_rn(xs[j]);
        *(s16x8*)&Bhi[e0] = h8;
    } else {
        int idx = (bi - 8000) * 256 + tid;   // 131072 = 2048 m x 64 k8
        int m = idx & 2047;
        int k8 = idx >> 11;
        int t = m >> 5, b = m & 31;
        const unsigned* Hs = H65 + (size_t)t * HSTEP;
        s16x8 h8;
#pragma unroll
        for (int j = 0; j < 8; ++j) {
            unsigned u = Hs[(size_t)b * 512 + k8 * 8 + j];
            h8[j] = (short)(u & 0xffffu);
        }
        *(s16x8*)&Ahi[(size_t)m * 512 + k8 * 8] = h8;
    }
}

// ---------------------------------------------------------------------------
// Kernel 5: FC as a plain bf16 MFMA GEMM: C = Ahi*Bhi (+bias). K = 512.
// 128x128 tile, 4 waves, K-step 64, global_load_lds(16), 16x16x32 bf16 MFMA.
// ---------------------------------------------------------------------------
__global__ __launch_bounds__(256) void fc_mfma_kernel(
    const short* __restrict__ Ahi, const short* __restrict__ Bhi,
    const float* __restrict__ bias, float* __restrict__ out)
{
    __shared__ short As[128 * 64];
    __shared__ short Bs[128 * 64];

    const int bi = blockIdx.x;
    const int wg = (bi & 7) * 500 + (bi >> 3);    // XCD-contiguous remap
    const int mt = wg & 15, nt = wg >> 4;
    const int m0 = mt * 128, n0 = nt * 128;
    const int tid = threadIdx.x;
    const int w = tid >> 6, lane = tid & 63;
    const int wm = w >> 1, wn = w & 1;
    const int srow = (lane >> 3);
    const int scol = (lane & 7) * 8;

    f32x4 acc[4][4] = {};

    for (int ks = 0; ks < 8; ++ks) {
        const int kco = ks * 64;
#pragma unroll
        for (int i = 0; i < 4; ++i) {
            int row = w * 32 + i * 8 + srow;
            gload_lds16(&Ahi[(size_t)(m0 + row) * 512 + kco + scol],
                        (void*)&As[w * 2048 + i * 512]);
            gload_lds16(&Bhi[(size_t)(n0 + row) * 512 + kco + scol],
                        (void*)&Bs[w * 2048 + i * 512]);
        }
        __syncthreads();

#pragma unroll
        for (int kk = 0; kk < 2; ++kk) {
            s16x8 af[4], bf[4];
#pragma unroll
            for (int f = 0; f < 4; ++f) {
                af[f] = *(const s16x8*)&As[(wm * 64 + f * 16 + (lane & 15)) * 64 + kk * 32 + (lane >> 4) * 8];
                bf[f] = *(const s16x8*)&Bs[(wn * 64 + f * 16 + (lane & 15)) * 64 + kk * 32 + (lane >> 4) * 8];
            }
#pragma unroll
            for (int fm = 0; fm < 4; ++fm)
#pragma unroll
                for (int fn = 0; fn < 4; ++fn)
                    acc[fm][fn] = __builtin_amdgcn_mfma_f32_16x16x32_bf16(
                        af[fm], bf[fn], acc[fm][fn], 0, 0, 0);
        }
        __syncthreads();
    }

    float bb[4];
#pragma unroll
    for (int fn = 0; fn < 4; ++fn)
        bb[fn] = bias[n0 + wn * 64 + fn * 16 + (lane & 15)];

#pragma unroll
    for (int fm = 0; fm < 4; ++fm) {
        int mbase = m0 + wm * 64 + fm * 16 + (lane >> 4) * 4;
#pragma unroll
        for (int r = 0; r < 4; ++r) {
            int m = mbase + r;
            int t = m >> 5, b = m & 31;
            float* orow = out + (size_t)(b * LSEQ + t) * VOC;
#pragma unroll
            for (int fn = 0; fn < 4; ++fn)
                orow[n0 + wn * 64 + fn * 16 + (lane & 15)] = acc[fm][fn][r] + bb[fn];
        }
    }
}

// ---------------------------------------------------------------------------
extern "C" void kernel_launch(void* const* d_in, const int* in_sizes, int n_in,
                              void* d_out, int out_size, void* d_ws, size_t ws_size,
                              hipStream_t stream)
{
    const int*   X    = (const int*)d_in[0];
    const int*   y    = (const int*)d_in[1];
    // d_in[2] = teacher_forcing (always 1, unused)
    const float* embX = (const float*)d_in[3];
    const float* WihE = (const float*)d_in[4];
    const float* WhhE = (const float*)d_in[5];
    const float* bE   = (const float*)d_in[6];
    const float* embY = (const float*)d_in[7];
    const float* WihD = (const float*)d_in[8];
    const float* WhhD = (const float*)d_in[9];
    const float* bD   = (const float*)d_in[10];
    const float* fcW  = (const float*)d_in[11];
    const float* fcB  = (const float*)d_in[12];
    float* out = (float*)d_out;

    char* ws = (char*)d_ws;
    const size_t XW_BYTES = (size_t)2048 * 2048 * 4;          // 16 MB each
    const size_t FL_BYTES = 64 * 1024;                        // flags (4 KB used)
    const size_t H_BYTES  = (size_t)129 * HSTEP * 4;          // 8.45 MB
    const size_t A_BYTES  = (size_t)2048 * HID * 2;           // 2 MB
    const size_t WP_BYTES = (size_t)G4 * HID * 2;             // 2 MB per plane

    float*    xwE   = (float*)(ws);
    float*    xwD   = (float*)(ws + XW_BYTES);
    int*      flags = (int*)(ws + 2 * XW_BYTES);
    unsigned* H32   = (unsigned*)(ws + 2 * XW_BYTES + FL_BYTES);
    short*    Ahi   = (short*)(ws + 2 * XW_BYTES + FL_BYTES + H_BYTES);
    short*    Bhi   = (short*)(ws);                           // aliases xw (dead post-lstm)
    char*     Wplanes = ws + 2 * XW_BYTES + FL_BYTES + H_BYTES + 2 * A_BYTES;
    short* WhE_hi = (short*)(Wplanes);
    short* WhE_lo = (short*)(Wplanes + WP_BYTES);
    short* WhD_hi = (short*)(Wplanes + 2 * WP_BYTES);
    short* WhD_lo = (short*)(Wplanes + 3 * WP_BYTES);

    // reset flags + H[0] (= h0 = 0) each launch: 128 KB total
    hipMemsetAsync((void*)flags, 0, FL_BYTES + (size_t)HSTEP * 4, stream);

    input_proj_kernel<<<dim3(32, 32, 3), 256, 0, stream>>>(
        X, y, embX, embY, WihE, WihD, bE, bD, xwE, xwD,
        WhhE, WhhD, WhE_hi, WhE_lo, WhD_hi, WhD_lo);

    {
        const float* a0 = xwE; const float* a1 = xwD;
        const short* a2 = WhE_hi; const short* a3 = WhE_lo;
        const short* a4 = WhD_hi; const short* a5 = WhD_lo;
        unsigned* a6 = H32; int* a7 = flags;
        void* args[] = {&a0, &a1, &a2, &a3, &a4, &a5, &a6, &a7};
        hipLaunchCooperativeKernel((const void*)lstm_coop_kernel, dim3(NBLK), dim3(NTHR),
                                   args, 0, stream);
    }

    convWA_kernel<<<8512, 256, 0, stream>>>(fcW, Bhi, H32 + (size_t)65 * HSTEP, Ahi);

    fc_mfma_kernel<<<4000, 256, 0, stream>>>(Ahi, Bhi, fcB, out);
}

// Round 21
// 784.147 us; speedup vs baseline: 1.9099x; 1.0002x over previous
//
#include <hip/hip_runtime.h>

#define HID 512
#define G4 2048      // 4*HID
#define LSEQ 64
#define VOC 32000
#define EMBD 256
#define NBLK 32      // lstm blocks: 2 batch-groups x 16 col-blocks
#define CONVBLK 64   // extra coop blocks doing fcW->Bhi conversion
#define NTHR 512     // 8 waves = 8 row-tiles (16 gate rows each)
#define HSTEP 16384  // u32 entries per per-step h buffer (64 KB): [b][col]

using s16x8 = __attribute__((ext_vector_type(8))) short;   // 8 bf16 (4 VGPR)
using f32x4 = __attribute__((ext_vector_type(4))) float;   // MFMA acc frag
using uintx4 = __attribute__((ext_vector_type(4))) unsigned; // 16B payload

__device__ inline unsigned short f2bf_rn(float x) {
    unsigned u = __float_as_uint(x);
    unsigned r = (u + 0x7fffu + ((u >> 16) & 1u)) >> 16;
    return (unsigned short)r;
}
__device__ inline float bf2f(unsigned short h) {
    return __uint_as_float(((unsigned)h) << 16);
}
__device__ inline void gload_lds16(const void* g, void* l) {
    __builtin_amdgcn_global_load_lds(
        (const __attribute__((address_space(1))) void*)g,
        (__attribute__((address_space(3))) void*)l, 16, 0, 0);
}

// ---------------------------------------------------------------------------
// Kernel 1 (merged): z<2 -> input projection (encoder/decoder), producing
// xwT[(t*2048 + g*512 + col)*32 + b]; z==2 -> WhhE/WhhD f32 -> bf16 hi/lo
// planes (convWhh, 1024 blocks' worth of work).
// ---------------------------------------------------------------------------
__global__ __launch_bounds__(256) void input_proj_kernel(
    const int* __restrict__ Xtok, const int* __restrict__ Ytok,
    const float* __restrict__ embX, const float* __restrict__ embY,
    const float* __restrict__ WE, const float* __restrict__ WD,
    const float* __restrict__ bE, const float* __restrict__ bD,
    float* __restrict__ xwE, float* __restrict__ xwD,
    const float* __restrict__ WhhE, const float* __restrict__ WhhD,
    short* __restrict__ HiE, short* __restrict__ LoE,
    short* __restrict__ HiD, short* __restrict__ LoD)
{
    const int tid = threadIdx.x;
    const int phase = blockIdx.z;

    if (phase == 2) {                    // convWhh plane
        int blk = blockIdx.y * 32 + blockIdx.x;       // 0..1023
        int idx = blk * 256 + tid;                    // 2 mats x 131072 chunks
        int m = idx >> 17;
        int e = idx & 131071;
        const float* W = m ? WhhD : WhhE;
        short* Hi = m ? HiD : HiE;
        short* Lo = m ? LoD : LoE;
        size_t e0 = (size_t)e * 8;
        float4 v0 = *(const float4*)&W[e0];
        float4 v1 = *(const float4*)&W[e0 + 4];
        float xs[8] = {v0.x, v0.y, v0.z, v0.w, v1.x, v1.y, v1.z, v1.w};
        s16x8 h8, l8;
#pragma unroll
        for (int j = 0; j < 8; ++j) {
            unsigned short hi = f2bf_rn(xs[j]);
            h8[j] = (short)hi;
            l8[j] = (short)f2bf_rn(xs[j] - bf2f(hi));
        }
        *(s16x8*)&Hi[e0] = h8;
        *(s16x8*)&Lo[e0] = l8;
        return;
    }

    __shared__ float Al[32][68];
    __shared__ float Bl[32][68];
    __shared__ float Cl[64][68];
    const int* tokens = phase ? Ytok : Xtok;
    const float* emb  = phase ? embY : embX;
    const float* W    = phase ? WD : WE;
    const float* bv   = phase ? bD : bE;
    float* outp       = phase ? xwD : xwE;

    const int m0 = blockIdx.x * 64;
    const int n0 = blockIdx.y * 64;
    const int tm = tid & 15;
    const int tn = tid >> 4;

    float acc[4][4] = {};

    for (int kc = 0; kc < EMBD; kc += 32) {
#pragma unroll
        for (int r = 0; r < 2; ++r) {
            int i = tid + r * 256;
            int am = i >> 3;
            int kq = i & 7;
            int m = m0 + am;
            int t = m >> 5, b = m & 31;
            int tok;
            if (phase) { int tt = (t == 0) ? 0 : (t - 1); tok = tokens[b * LSEQ + tt]; }
            else       { tok = tokens[b * LSEQ + t]; }
            float4 av = *(const float4*)&emb[(size_t)tok * EMBD + kc + kq * 4];
            Al[kq * 4 + 0][am] = av.x; Al[kq * 4 + 1][am] = av.y;
            Al[kq * 4 + 2][am] = av.z; Al[kq * 4 + 3][am] = av.w;
            float4 wv = *(const float4*)&W[(size_t)(n0 + am) * EMBD + kc + kq * 4];
            Bl[kq * 4 + 0][am] = wv.x; Bl[kq * 4 + 1][am] = wv.y;
            Bl[kq * 4 + 2][am] = wv.z; Bl[kq * 4 + 3][am] = wv.w;
        }
        __syncthreads();
#pragma unroll
        for (int k = 0; k < 32; ++k) {
            float4 a  = *(const float4*)&Al[k][tm * 4];
            float4 b4 = *(const float4*)&Bl[k][tn * 4];
            acc[0][0] += a.x * b4.x; acc[0][1] += a.x * b4.y; acc[0][2] += a.x * b4.z; acc[0][3] += a.x * b4.w;
            acc[1][0] += a.y * b4.x; acc[1][1] += a.y * b4.y; acc[1][2] += a.y * b4.z; acc[1][3] += a.y * b4.w;
            acc[2][0] += a.z * b4.x; acc[2][1] += a.z * b4.y; acc[2][2] += a.z * b4.z; acc[2][3] += a.z * b4.w;
            acc[3][0] += a.w * b4.x; acc[3][1] += a.w * b4.y; acc[3][2] += a.w * b4.z; acc[3][3] += a.w * b4.w;
        }
        __syncthreads();
    }

    float4 bb = *(const float4*)&bv[n0 + tn * 4];
#pragma unroll
    for (int r = 0; r < 4; ++r) {
        Cl[tn * 4 + 0][tm * 4 + r] = acc[r][0] + bb.x;
        Cl[tn * 4 + 1][tm * 4 + r] = acc[r][1] + bb.y;
        Cl[tn * 4 + 2][tm * 4 + r] = acc[r][2] + bb.z;
        Cl[tn * 4 + 3][tm * 4 + r] = acc[r][3] + bb.w;
    }
    __syncthreads();

    const int t0 = m0 >> 5;
#pragma unroll
    for (int r = 0; r < 4; ++r) {
        int f = tid + r * 256;
        int nl = f >> 4;
        int rem = f & 15;
        int tp = rem >> 3;
        int bq = rem & 7;
        float4 v = *(const float4*)&Cl[nl][tp * 32 + bq * 4];
        *(float4*)&outp[((size_t)(t0 + tp) * G4 + n0 + nl) * 32 + bq * 4] = v;
    }
}

// ---------------------------------------------------------------------------
// Kernel 2: LSTM recurrence on matrix cores — batch-grouped exchange (EXACT
// R17/R18/R20 protocol, best measured 542 us), plus CONVBLK extra blocks
// (bid >= NBLK) that grid-stride the fcW -> Bhi bf16 conversion concurrently
// on otherwise-idle CUs (they never touch LDS, flags, or sync).
// LSTM: 2 groups x 16 blocks; group g owns batches 16g..16g+15; block owns
// 32 h-cols (128 gate rows). 8 waves = 8 row-tiles of 16 (rows m = c*4+gate,
// C-frag reg r = gate r). Per step: poll 16 group flags (f >= s); stage
// (4 x 16B sc1 + 4 x ds_write_b128, bijective XOR swizzle); B1; 16kt x
// {2 x ds_read_b128 + unpack + 3 MFMA}; in-reg gates; publish u32;
// __syncthreads (vmcnt0 drain, in-CU join); tid0 single RELEASE flag store.
// ---------------------------------------------------------------------------
__global__ __launch_bounds__(512, 2) void lstm_coop_kernel(
    const float* __restrict__ xwE, const float* __restrict__ xwD,
    const short* __restrict__ WhE_hi, const short* __restrict__ WhE_lo,
    const short* __restrict__ WhD_hi, const short* __restrict__ WhD_lo,
    unsigned* __restrict__ H32, int* __restrict__ flags,
    const float* __restrict__ fcW, short* __restrict__ Bhi)
{
    __shared__ unsigned hbu[16 * 512];   // 32 KB, [b_local][col] u32, swizzled

    const int tid = threadIdx.x;
    const int bid = blockIdx.x;

    if (bid >= NBLK) {                   // overlapped convW: fcW -> Bhi
        const size_t nchunk = (size_t)VOC * HID / 8;
        const size_t stride = (size_t)(gridDim.x - NBLK) * NTHR;
        for (size_t idx = (size_t)(bid - NBLK) * NTHR + tid; idx < nchunk;
             idx += stride) {
            size_t e0 = idx * 8;
            float4 v0 = *(const float4*)&fcW[e0];
            float4 v1 = *(const float4*)&fcW[e0 + 4];
            float xs[8] = {v0.x, v0.y, v0.z, v0.w, v1.x, v1.y, v1.z, v1.w};
            s16x8 h8;
#pragma unroll
            for (int j = 0; j < 8; ++j)
                h8[j] = (short)f2bf_rn(xs[j]);
            *(s16x8*)&Bhi[e0] = h8;
        }
        return;
    }

    const int g  = bid >> 4;             // batch group 0..1
    const int kb = bid & 15;             // col-block within group
    const int c0 = kb * 32;              // first of 32 owned cols
    const int gb0 = g * 16;              // group's first global batch
    const int lane = tid & 63;
    const int w = tid >> 6;              // 8 waves = 8 row-tiles
    const int arow = lane & 15;          // A-frag row within tile
    const int koffq = (lane >> 4) * 2;   // quad base within kt
    // B-frag read bases (local batch row, swizzled)
    const int bbl = lane & 15;
    const unsigned keyr = (unsigned)(bbl & 7);
    const unsigned rb0 = (unsigned)bbl * 2048 + (((unsigned)koffq ^ keyr) << 4);
    const unsigned rb1 = (unsigned)bbl * 2048 + (((unsigned)(koffq + 1) ^ keyr) << 4);
    // staging: local row sbl = 2w + (lane>>5), quad sq = lane&31 (+32k)
    const int sbl = 2 * w + (lane >> 5);
    const int sq = lane & 31;
    const unsigned wswz = (((unsigned)(sq & 7) ^ (unsigned)(sbl & 7)) | (unsigned)(sq & 24));
    const unsigned wbase = (unsigned)sbl * 2048 + (wswz << 4);
    // output mapping
    const int col0 = c0 + 4 * w + (lane >> 4);
    const int bpub = gb0 + (lane & 15);
    float creg = 0.f;

    s16x8 AH[16], AL[16];                // Whh hi/lo frags (per-phase resident)

    for (int s = 0; s < 2 * LSEQ; ++s) {
        const int phase = s >> 6;
        const int t = s & 63;
        if (t == 0) {                    // (re)load A frags for this phase
            const short* WH = phase ? WhD_hi : WhE_hi;
            const short* WL = phase ? WhD_lo : WhE_lo;
            const int gr = (arow & 3) * 512 + c0 + 4 * w + (arow >> 2);
            const size_t ab = (size_t)gr * 512 + (lane >> 4) * 8;
#pragma unroll
            for (int kt = 0; kt < 16; ++kt) {
                AH[kt] = *(const s16x8*)&WH[ab + kt * 32];
                AL[kt] = *(const s16x8*)&WL[ab + kt * 32];
            }
        }

        // xw prefetch (h-independent; drained by the staging vmcnt(0))
        const float* xw = phase ? xwD : xwE;
        size_t xb = ((size_t)t * G4 + col0) * 32 + bpub;
        float xg0 = xw[xb];
        float xg1 = xw[xb + 1 * 512 * 32];
        float xg2 = xw[xb + 2 * 512 * 32];
        float xg3 = xw[xb + 3 * 512 * 32];

        // poll this group's 16 producer flags with one wave-load per round
        {
            const int* flagp = flags + (g * 16 + (lane & 15)) * 32;  // 128B lines
            for (;;) {
                int f = __hip_atomic_load(flagp, __ATOMIC_RELAXED,
                                          __HIP_MEMORY_SCOPE_AGENT);
                if (__all(f >= s)) break;
                __builtin_amdgcn_s_sleep(1);
            }
        }
        __builtin_amdgcn_sched_barrier(0);

        // stage: 4 x 16B sc1 loads -> ONE vmcnt(0) -> 4 x ds_write_b128
        const char* sbase = (const char*)(H32 + (size_t)s * HSTEP
                                          + (size_t)(gb0 + sbl) * 512) + sq * 16;
        uintx4 v[4];
#pragma unroll
        for (int k = 0; k < 4; ++k)
            asm volatile("global_load_dwordx4 %0, %1, off offset:%c2 sc1"
                         : "=v"(v[k]) : "v"(sbase), "i"(k * 512));
        asm volatile("s_waitcnt vmcnt(0)" ::: "memory");
        __builtin_amdgcn_sched_barrier(0);
#pragma unroll
        for (int k = 0; k < 4; ++k)
            *(uintx4*)((char*)hbu + wbase + k * 512) = v[k];
        asm volatile("s_waitcnt lgkmcnt(0)\ns_barrier" ::: "memory");  // B1

        // MFMA: per kt read one B-frag (2 x b128 swizzled), 3 MFMAs
        f32x4 a0 = {}, a1 = {}, a2 = {};
#pragma unroll
        for (int kt = 0; kt < 16; ++kt) {
            uintx4 q0 = *(const uintx4*)((const char*)hbu + rb0 + kt * 128);
            uintx4 q1 = *(const uintx4*)((const char*)hbu + rb1 + kt * 128);
            uintx4 bh, bl;
            bh[0] = (q0[0] & 0xffffu) | (q0[1] << 16);
            bh[1] = (q0[2] & 0xffffu) | (q0[3] << 16);
            bh[2] = (q1[0] & 0xffffu) | (q1[1] << 16);
            bh[3] = (q1[2] & 0xffffu) | (q1[3] << 16);
            bl[0] = (q0[0] >> 16) | (q0[1] & 0xffff0000u);
            bl[1] = (q0[2] >> 16) | (q0[3] & 0xffff0000u);
            bl[2] = (q1[0] >> 16) | (q1[1] & 0xffff0000u);
            bl[3] = (q1[2] >> 16) | (q1[3] & 0xffff0000u);
            s16x8 bhv = __builtin_bit_cast(s16x8, bh);
            s16x8 blv = __builtin_bit_cast(s16x8, bl);
            a0 = __builtin_amdgcn_mfma_f32_16x16x32_bf16(AH[kt], bhv, a0, 0, 0, 0);
            a1 = __builtin_amdgcn_mfma_f32_16x16x32_bf16(AL[kt], bhv, a1, 0, 0, 0);
            a2 = __builtin_amdgcn_mfma_f32_16x16x32_bf16(AH[kt], blv, a2, 0, 0, 0);
        }

        // gates fully in-register (C-frag reg r = gate r); one publish/lane
        {
            float gi = xg0 + a0[0] + a1[0] + a2[0];
            float gf = xg1 + a0[1] + a1[1] + a2[1];
            float gg = xg2 + a0[2] + a1[2] + a2[2];
            float go = xg3 + a0[3] + a1[3] + a2[3];
            float si = 1.f / (1.f + __expf(-gi));
            float sf = 1.f / (1.f + __expf(-gf));
            float so = 1.f / (1.f + __expf(-go));
            float tg = tanhf(gg);
            float c = sf * creg + si * tg;
            creg = c;
            float h = so * tanhf(c);
            unsigned hi = f2bf_rn(h);
            unsigned lo = f2bf_rn(h - bf2f((unsigned short)hi));
            __hip_atomic_store(
                H32 + (size_t)(s + 1) * HSTEP + (size_t)bpub * 512 + col0,
                hi | (lo << 16), __ATOMIC_RELAXED, __HIP_MEMORY_SCOPE_AGENT);
        }
        __syncthreads();   // vmcnt(0) drain + in-CU block join
        if (tid == 0)
            __hip_atomic_store(&flags[bid * 32], s + 1,
                               __ATOMIC_RELEASE, __HIP_MEMORY_SCOPE_AGENT);
    }
}

// ---------------------------------------------------------------------------
// Kernel 4: decoder H (u32 hilo, [b][col]) -> Ahi bf16 [2048][512].
// ---------------------------------------------------------------------------
__global__ __launch_bounds__(256) void convA_kernel(
    const unsigned* __restrict__ H65, short* __restrict__ Ahi)
{
    int idx = blockIdx.x * 256 + threadIdx.x;   // 131072 = 2048 m x 64 k8
    int m = idx & 2047;
    int k8 = idx >> 11;
    int t = m >> 5, b = m & 31;
    const unsigned* Hs = H65 + (size_t)t * HSTEP;
    s16x8 h8;
#pragma unroll
    for (int j = 0; j < 8; ++j) {
        unsigned u = Hs[(size_t)b * 512 + k8 * 8 + j];
        h8[j] = (short)(u & 0xffffu);
    }
    *(s16x8*)&Ahi[(size_t)m * 512 + k8 * 8] = h8;
}

// ---------------------------------------------------------------------------
// Kernel 5: FC as a plain bf16 MFMA GEMM: C = Ahi*Bhi (+bias). K = 512.
// 128x128 tile, 4 waves, K-step 64, global_load_lds(16), 16x16x32 bf16 MFMA.
// ---------------------------------------------------------------------------
__global__ __launch_bounds__(256) void fc_mfma_kernel(
    const short* __restrict__ Ahi, const short* __restrict__ Bhi,
    const float* __restrict__ bias, float* __restrict__ out)
{
    __shared__ short As[128 * 64];
    __shared__ short Bs[128 * 64];

    const int bi = blockIdx.x;
    const int wg = (bi & 7) * 500 + (bi >> 3);    // XCD-contiguous remap
    const int mt = wg & 15, nt = wg >> 4;
    const int m0 = mt * 128, n0 = nt * 128;
    const int tid = threadIdx.x;
    const int w = tid >> 6, lane = tid & 63;
    const int wm = w >> 1, wn = w & 1;
    const int srow = (lane >> 3);
    const int scol = (lane & 7) * 8;

    f32x4 acc[4][4] = {};

    for (int ks = 0; ks < 8; ++ks) {
        const int kco = ks * 64;
#pragma unroll
        for (int i = 0; i < 4; ++i) {
            int row = w * 32 + i * 8 + srow;
            gload_lds16(&Ahi[(size_t)(m0 + row) * 512 + kco + scol],
                        (void*)&As[w * 2048 + i * 512]);
            gload_lds16(&Bhi[(size_t)(n0 + row) * 512 + kco + scol],
                        (void*)&Bs[w * 2048 + i * 512]);
        }
        __syncthreads();

#pragma unroll
        for (int kk = 0; kk < 2; ++kk) {
            s16x8 af[4], bf[4];
#pragma unroll
            for (int f = 0; f < 4; ++f) {
                af[f] = *(const s16x8*)&As[(wm * 64 + f * 16 + (lane & 15)) * 64 + kk * 32 + (lane >> 4) * 8];
                bf[f] = *(const s16x8*)&Bs[(wn * 64 + f * 16 + (lane & 15)) * 64 + kk * 32 + (lane >> 4) * 8];
            }
#pragma unroll
            for (int fm = 0; fm < 4; ++fm)
#pragma unroll
                for (int fn = 0; fn < 4; ++fn)
                    acc[fm][fn] = __builtin_amdgcn_mfma_f32_16x16x32_bf16(
                        af[fm], bf[fn], acc[fm][fn], 0, 0, 0);
        }
        __syncthreads();
    }

    float bb[4];
#pragma unroll
    for (int fn = 0; fn < 4; ++fn)
        bb[fn] = bias[n0 + wn * 64 + fn * 16 + (lane & 15)];

#pragma unroll
    for (int fm = 0; fm < 4; ++fm) {
        int mbase = m0 + wm * 64 + fm * 16 + (lane >> 4) * 4;
#pragma unroll
        for (int r = 0; r < 4; ++r) {
            int m = mbase + r;
            int t = m >> 5, b = m & 31;
            float* orow = out + (size_t)(b * LSEQ + t) * VOC;
#pragma unroll
            for (int fn = 0; fn < 4; ++fn)
                orow[n0 + wn * 64 + fn * 16 + (lane & 15)] = acc[fm][fn][r] + bb[fn];
        }
    }
}

// ---------------------------------------------------------------------------
extern "C" void kernel_launch(void* const* d_in, const int* in_sizes, int n_in,
                              void* d_out, int out_size, void* d_ws, size_t ws_size,
                              hipStream_t stream)
{
    const int*   X    = (const int*)d_in[0];
    const int*   y    = (const int*)d_in[1];
    // d_in[2] = teacher_forcing (always 1, unused)
    const float* embX = (const float*)d_in[3];
    const float* WihE = (const float*)d_in[4];
    const float* WhhE = (const float*)d_in[5];
    const float* bE   = (const float*)d_in[6];
    const float* embY = (const float*)d_in[7];
    const float* WihD = (const float*)d_in[8];
    const float* WhhD = (const float*)d_in[9];
    const float* bD   = (const float*)d_in[10];
    const float* fcW  = (const float*)d_in[11];
    const float* fcB  = (const float*)d_in[12];
    float* out = (float*)d_out;

    char* ws = (char*)d_ws;
    const size_t XW_BYTES = (size_t)2048 * 2048 * 4;          // 16 MB each
    const size_t FL_BYTES = 64 * 1024;                        // flags (4 KB used)
    const size_t H_BYTES  = (size_t)129 * HSTEP * 4;          // 8.45 MB
    const size_t A_BYTES  = (size_t)2048 * HID * 2;           // 2 MB
    const size_t WP_BYTES = (size_t)G4 * HID * 2;             // 2 MB per plane

    float*    xwE   = (float*)(ws);
    float*    xwD   = (float*)(ws + XW_BYTES);
    int*      flags = (int*)(ws + 2 * XW_BYTES);
    unsigned* H32   = (unsigned*)(ws + 2 * XW_BYTES + FL_BYTES);
    short*    Ahi   = (short*)(ws + 2 * XW_BYTES + FL_BYTES + H_BYTES);
    // Bhi moved OUT of the xw alias region: written concurrently with the
    // lstm (which still reads xw), so it gets its own slot after Ahi.
    short*    Bhi   = (short*)(ws + 2 * XW_BYTES + FL_BYTES + H_BYTES + A_BYTES);
    char*     Wplanes = ws + 2 * XW_BYTES + FL_BYTES + H_BYTES + A_BYTES
                         + (size_t)VOC * HID * 2;
    short* WhE_hi = (short*)(Wplanes);
    short* WhE_lo = (short*)(Wplanes + WP_BYTES);
    short* WhD_hi = (short*)(Wplanes + 2 * WP_BYTES);
    short* WhD_lo = (short*)(Wplanes + 3 * WP_BYTES);

    // reset flags + H[0] (= h0 = 0) each launch: 128 KB total
    hipMemsetAsync((void*)flags, 0, FL_BYTES + (size_t)HSTEP * 4, stream);

    input_proj_kernel<<<dim3(32, 32, 3), 256, 0, stream>>>(
        X, y, embX, embY, WihE, WihD, bE, bD, xwE, xwD,
        WhhE, WhhD, WhE_hi, WhE_lo, WhD_hi, WhD_lo);

    {
        const float* a0 = xwE; const float* a1 = xwD;
        const short* a2 = WhE_hi; const short* a3 = WhE_lo;
        const short* a4 = WhD_hi; const short* a5 = WhD_lo;
        unsigned* a6 = H32; int* a7 = flags;
        const float* a8 = fcW; short* a9 = Bhi;
        void* args[] = {&a0, &a1, &a2, &a3, &a4, &a5, &a6, &a7, &a8, &a9};
        hipLaunchCooperativeKernel((const void*)lstm_coop_kernel,
                                   dim3(NBLK + CONVBLK), dim3(NTHR),
                                   args, 0, stream);
    }

    convA_kernel<<<512, 256, 0, stream>>>(H32 + (size_t)65 * HSTEP, Ahi);

    fc_mfma_kernel<<<4000, 256, 0, stream>>>(Ahi, Bhi, fcB, out);
}